// Round 1
// baseline (115.653 us; speedup 1.0000x reference)
//
#include <hip/hip_runtime.h>
#include <hip/hip_bf16.h>

#define BB 32
#define NN 2048
#define DI 16
#define KK 32
#define DOUT 16

// workspace layout (bytes):
//  u_pk  : [B][N][K][8] u32 (bf16 z-pairs)      64 MiB   @ 0
//  t_part: [512][B*K*16] f32                    32 MiB   @ 67108864
//  t     : [B][K][16] f32                       64 KiB   @ 100663296
//  l/c   : [B][N][K] f32 (in-place softmax)      8 MiB   @ 100728832
//  s_part: [8][B*K*16] f32                     512 KiB   @ 109117440
#define WS_U     0
#define WS_TPART 67108864UL
#define WS_T     100663296UL
#define WS_L     100728832UL
#define WS_SPART 109117440UL
#define WS_NEED  109641728UL

__device__ __forceinline__ float bf_lo(unsigned v) { return __uint_as_float(v << 16); }
__device__ __forceinline__ float bf_hi(unsigned v) { return __uint_as_float(v & 0xffff0000u); }
__device__ __forceinline__ unsigned pack_bf16(float a, float b) {
    unsigned ua = __float_as_uint(a), ub = __float_as_uint(b);
    return ((ua + 0x8000u) >> 16) | ((ub + 0x8000u) & 0xffff0000u);
}

// ---------------- K1: u (bf16 packed) + t partials --------------------------
// grid 512, block 256. thread: zp = tid&7 (z-pair), k = tid>>3. j-chunk = 4.
__global__ __launch_bounds__(256, 2)
void k1_u_t(const float* __restrict__ x, const float* __restrict__ w,
            unsigned* __restrict__ u_pk, float* __restrict__ t_part)
{
    const int tid = threadIdx.x;
    const int zp  = tid & 7;
    const int k   = tid >> 3;
    const int blk = blockIdx.x;
    const int j0  = blk * 4;

    float tac0[BB], tac1[BB];
#pragma unroll
    for (int b = 0; b < BB; ++b) { tac0[b] = 0.f; tac1[b] = 0.f; }

#pragma unroll 1
    for (int jj = 0; jj < 4; ++jj) {
        const int j = j0 + jj;
        // w[k][j][i][2zp + {0,1}], i = 0..15
        const float2* wp = reinterpret_cast<const float2*>(
            w + (((size_t)k * NN + j) * DI) * DOUT + 2 * zp);
        float2 wr[16];
#pragma unroll
        for (int i = 0; i < 16; ++i) wr[i] = wp[i * 8];

        unsigned* __restrict__ ubase = u_pk + ((size_t)j * KK + k) * 8 + zp;

#pragma unroll
        for (int b = 0; b < BB; ++b) {
            const float* __restrict__ xr = x + ((size_t)b * NN + j) * DI; // wave-uniform
            float xs[16];
#pragma unroll
            for (int i = 0; i < 16; ++i) xs[i] = xr[i];
            float u0 = 0.f, u1 = 0.f;
#pragma unroll
            for (int i = 0; i < 16; ++i) {
                u0 = fmaf(xs[i], wr[i].x, u0);
                u1 = fmaf(xs[i], wr[i].y, u1);
            }
            tac0[b] += u0; tac1[b] += u1;
            ubase[(size_t)b * (NN * KK * 8)] = pack_bf16(u0, u1);
        }
    }

    float2* tp = reinterpret_cast<float2*>(t_part + (size_t)blk * 16384);
#pragma unroll
    for (int b = 0; b < BB; ++b) {
        float2 v; v.x = tac0[b]; v.y = tac1[b];
        tp[(b * KK + k) * 8 + zp] = v;
    }
}

// ---------------- K2a: reduce 512 t partials --------------------------------
// grid 64, block 1024: lane = idx within 256-chunk, q = s-quarter.
__global__ __launch_bounds__(1024)
void k2a_treduce(const float* __restrict__ t_part, float* __restrict__ t)
{
    __shared__ float red[1024];
    const int lane = threadIdx.x & 255;
    const int q    = threadIdx.x >> 8;
    const int idx  = blockIdx.x * 256 + lane;
    float a0 = 0.f, a1 = 0.f, a2 = 0.f, a3 = 0.f;
    const int s0 = q * 128;
#pragma unroll 2
    for (int s = s0; s < s0 + 128; s += 4) {
        a0 += t_part[(size_t)(s + 0) * 16384 + idx];
        a1 += t_part[(size_t)(s + 1) * 16384 + idx];
        a2 += t_part[(size_t)(s + 2) * 16384 + idx];
        a3 += t_part[(size_t)(s + 3) * 16384 + idx];
    }
    red[threadIdx.x] = (a0 + a1) + (a2 + a3);
    __syncthreads();
    if (q == 0)
        t[idx] = (red[lane] + red[lane + 256]) + (red[lane + 512] + red[lane + 768]);
}

// ---------------- K2bi: logits l[b][j][k] = <u, t> --------------------------
// grid 2048 (= 32 b * 64 j-chunks of 32), block 256: k = tid&31, jl = tid>>5.
__global__ __launch_bounds__(256)
void k2bi_logits(const unsigned* __restrict__ u_pk, const float* __restrict__ t,
                 float* __restrict__ l)
{
    const int tid = threadIdx.x;
    const int k   = tid & 31;
    const int jl  = tid >> 5;
    const int b   = blockIdx.x >> 6;
    const int j00 = (blockIdx.x & 63) * 32;

    float tr[16];
    const float4* tp = reinterpret_cast<const float4*>(t + ((size_t)(b * KK + k)) * DOUT);
#pragma unroll
    for (int qq = 0; qq < 4; ++qq) {
        float4 v = tp[qq];
        tr[4 * qq + 0] = v.x; tr[4 * qq + 1] = v.y; tr[4 * qq + 2] = v.z; tr[4 * qq + 3] = v.w;
    }

#pragma unroll 1
    for (int jj = 0; jj < 4; ++jj) {
        const int j = j00 + jj * 8 + jl;
        const uint4* up = reinterpret_cast<const uint4*>(
            u_pk + (((size_t)b * NN + j) * KK + k) * 8);
        uint4 a = up[0], d = up[1];
        float acc0 = 0.f, acc1 = 0.f;
        acc0 = fmaf(bf_lo(a.x), tr[0],  acc0); acc1 = fmaf(bf_hi(a.x), tr[1],  acc1);
        acc0 = fmaf(bf_lo(a.y), tr[2],  acc0); acc1 = fmaf(bf_hi(a.y), tr[3],  acc1);
        acc0 = fmaf(bf_lo(a.z), tr[4],  acc0); acc1 = fmaf(bf_hi(a.z), tr[5],  acc1);
        acc0 = fmaf(bf_lo(a.w), tr[6],  acc0); acc1 = fmaf(bf_hi(a.w), tr[7],  acc1);
        acc0 = fmaf(bf_lo(d.x), tr[8],  acc0); acc1 = fmaf(bf_hi(d.x), tr[9],  acc1);
        acc0 = fmaf(bf_lo(d.y), tr[10], acc0); acc1 = fmaf(bf_hi(d.y), tr[11], acc1);
        acc0 = fmaf(bf_lo(d.z), tr[12], acc0); acc1 = fmaf(bf_hi(d.z), tr[13], acc1);
        acc0 = fmaf(bf_lo(d.w), tr[14], acc0); acc1 = fmaf(bf_hi(d.w), tr[15], acc1);
        l[((size_t)b * NN + j) * KK + k] = acc0 + acc1;
    }
}

// ---------------- K2bii: softmax over k (in-register) + bias, in-place ------
// grid 256 (= 32 b * 8 j-chunks of 256), block 256: thread = one (b, j).
__global__ __launch_bounds__(256)
void k2bii_softmax(float* __restrict__ lc, const float* __restrict__ bias)
{
    __shared__ float bs[KK][256];
    const int tid = threadIdx.x;
    const int b   = blockIdx.x >> 3;
    const int j0  = (blockIdx.x & 7) * 256;
#pragma unroll
    for (int k = 0; k < KK; ++k) bs[k][tid] = bias[(size_t)k * NN + j0 + tid];
    __syncthreads();

    const int j = j0 + tid;
    float4* lp = reinterpret_cast<float4*>(lc + ((size_t)b * NN + j) * KK);
    float lv[KK];
#pragma unroll
    for (int qq = 0; qq < 8; ++qq) {
        float4 v = lp[qq];
        lv[4 * qq + 0] = v.x; lv[4 * qq + 1] = v.y; lv[4 * qq + 2] = v.z; lv[4 * qq + 3] = v.w;
    }
    float m = lv[0];
#pragma unroll
    for (int k = 1; k < KK; ++k) m = fmaxf(m, lv[k]);
    float sum = 0.f;
#pragma unroll
    for (int k = 0; k < KK; ++k) { lv[k] = __expf((lv[k] - m) * 0.25f); sum += lv[k]; }
    const float inv = 1.f / sum;
#pragma unroll
    for (int k = 0; k < KK; ++k) lv[k] = lv[k] * inv + bs[k][tid];
#pragma unroll
    for (int qq = 0; qq < 8; ++qq) {
        float4 v; v.x = lv[4 * qq + 0]; v.y = lv[4 * qq + 1]; v.z = lv[4 * qq + 2]; v.w = lv[4 * qq + 3];
        lp[qq] = v;
    }
}

// ---------------- K3: s partials over j-slices ------------------------------
// grid 256 (= 32 b * 8 slices), block 256: zp = tid&7, k = tid>>3.
__global__ __launch_bounds__(256)
void k3_s(const unsigned* __restrict__ u_pk, const float* __restrict__ c,
          float* __restrict__ s_part)
{
    const int tid = threadIdx.x;
    const int zp  = tid & 7;
    const int k   = tid >> 3;
    const int b   = blockIdx.x >> 3;
    const int sl  = blockIdx.x & 7;

    float s0 = 0.f, s1 = 0.f;
    const unsigned* __restrict__ up = u_pk + (((size_t)b * NN + sl * 256) * KK + k) * 8 + zp;
    const float* __restrict__ cp    = c + ((size_t)b * NN + sl * 256) * KK + k;
#pragma unroll 4
    for (int jj = 0; jj < 256; ++jj) {
        unsigned uv = up[(size_t)jj * (KK * 8)];
        float cv    = cp[(size_t)jj * KK];
        s0 = fmaf(cv, bf_lo(uv), s0);
        s1 = fmaf(cv, bf_hi(uv), s1);
    }
    float2 v; v.x = s0; v.y = s1;
    *reinterpret_cast<float2*>(s_part + (size_t)sl * 16384 + ((b * KK + k) * DOUT + 2 * zp)) = v;
}

// ---------------- K4: reduce slices + squash --------------------------------
// grid 64, block 256: thread per (b,k,z); z = lane&15 -> shuffle norm.
__global__ __launch_bounds__(256)
void k4_squash(const float* __restrict__ s_part, float* __restrict__ out)
{
    const int idx = blockIdx.x * 256 + threadIdx.x;
    float s = 0.f;
#pragma unroll
    for (int p = 0; p < 8; ++p) s += s_part[(size_t)p * 16384 + idx];
    float ss = s * s;
    ss += __shfl_xor(ss, 1);
    ss += __shfl_xor(ss, 2);
    ss += __shfl_xor(ss, 4);
    ss += __shfl_xor(ss, 8);
    const float n = sqrtf(ss);
    out[idx] = (1.f - 1.f / (__expf(n) + 1e-20f)) * (s / (n + 1e-20f));
}

// sentinel if workspace too small (diagnosable absmax ~12345)
__global__ void k_sentinel(float* __restrict__ out)
{
    out[blockIdx.x * 256 + threadIdx.x] = 12345.0f;
}

extern "C" void kernel_launch(void* const* d_in, const int* in_sizes, int n_in,
                              void* d_out, int out_size, void* d_ws, size_t ws_size,
                              hipStream_t stream)
{
    const float* x    = (const float*)d_in[0];
    const float* w    = (const float*)d_in[1];
    const float* bias = (const float*)d_in[2];
    float* out        = (float*)d_out;

    char* ws = (char*)d_ws;
    if (ws_size < WS_NEED) {
        k_sentinel<<<dim3(64), dim3(256), 0, stream>>>(out);
        return;
    }
    unsigned* u_pk  = (unsigned*)(ws + WS_U);
    float* t_part   = (float*)(ws + WS_TPART);
    float* t        = (float*)(ws + WS_T);
    float* lc       = (float*)(ws + WS_L);
    float* s_part   = (float*)(ws + WS_SPART);

    k1_u_t       <<<dim3(512),  dim3(256),  0, stream>>>(x, w, u_pk, t_part);
    k2a_treduce  <<<dim3(64),   dim3(1024), 0, stream>>>(t_part, t);
    k2bi_logits  <<<dim3(2048), dim3(256),  0, stream>>>(u_pk, t, lc);
    k2bii_softmax<<<dim3(256),  dim3(256),  0, stream>>>(lc, bias);
    k3_s         <<<dim3(256),  dim3(256),  0, stream>>>(u_pk, lc, s_part);
    k4_squash    <<<dim3(64),   dim3(256),  0, stream>>>(s_part, out);
}

// Round 2
// 71.033 us; speedup vs baseline: 1.6282x; 1.6282x over previous
//
#include <hip/hip_runtime.h>

#define NN 2048
#define KK 32

// workspace layout (bytes):
//  u_pk   : [32 b][2048 j][32 k][8 zp] u32 (bf16 z-pairs)  64 MiB @ 0
//  t_part2: [32 b][8 sl][512] f32                         512 KiB @ 67108864
//  t      : [32 b][32 k][16 z] f32                         64 KiB @ 67633152
//  s_part : [32 b][64 jc][512] f32                          4 MiB @ 67698688
#define WS_U     0
#define WS_TP2   67108864UL
#define WS_T     67633152UL
#define WS_SPART 67698688UL
#define WS_NEED  71892992UL

__device__ __forceinline__ float bf_lo(unsigned v) { return __uint_as_float(v << 16); }
__device__ __forceinline__ float bf_hi(unsigned v) { return __uint_as_float(v & 0xffff0000u); }
__device__ __forceinline__ unsigned pack_bf16(float a, float b) {
    unsigned ua = __float_as_uint(a), ub = __float_as_uint(b);
    return ((ua + 0x8000u) >> 16) | ((ub + 0x8000u) & 0xffff0000u);
}

// ---------------- K1: pure projection u = x @ w (bf16 packed) ---------------
// grid 2048 (one j per block), block 256: zp = tid&7, k = tid>>3.
// w slice in registers (read exactly once), x row via LDS broadcast.
__global__ __launch_bounds__(256)
void k1_u(const float* __restrict__ x, const float* __restrict__ w,
          unsigned* __restrict__ u_pk)
{
    __shared__ float x_lds[32][16];
    const int tid = threadIdx.x;
    const int j   = blockIdx.x;
    const int zp  = tid & 7;
    const int k   = tid >> 3;

    if (tid < 128) {
        const int b = tid >> 2, q = tid & 3;
        const float4 v = *reinterpret_cast<const float4*>(
            x + ((size_t)b * NN + j) * 16 + q * 4);
        *reinterpret_cast<float4*>(&x_lds[b][q * 4]) = v;
    }

    // w[k][j][i][2zp + {0,1}], i = 0..15  (each element read exactly once)
    const float2* wp = reinterpret_cast<const float2*>(
        w + (((size_t)k * NN + j) * 16) * 16 + 2 * zp);
    float2 wr[16];
#pragma unroll
    for (int i = 0; i < 16; ++i) wr[i] = wp[i * 8];

    __syncthreads();

    unsigned* __restrict__ ub = u_pk + ((size_t)j * KK + k) * 8 + zp;
#pragma unroll 4
    for (int b = 0; b < 32; ++b) {
        float xs[16];
#pragma unroll
        for (int q = 0; q < 4; ++q) {
            float4 v = *reinterpret_cast<const float4*>(&x_lds[b][q * 4]);
            xs[q * 4 + 0] = v.x; xs[q * 4 + 1] = v.y;
            xs[q * 4 + 2] = v.z; xs[q * 4 + 3] = v.w;
        }
        float u0 = 0.f, u1 = 0.f;
#pragma unroll
        for (int i = 0; i < 16; ++i) {
            u0 = fmaf(xs[i], wr[i].x, u0);
            u1 = fmaf(xs[i], wr[i].y, u1);
        }
        ub[(size_t)b * (NN * KK * 8)] = pack_bf16(u0, u1);
    }
}

// ---------------- K2a: t partials = sum over j-slices of u ------------------
// grid 256 (= 32 b * 8 slices), block 1024: js = tid>>8, slot = tid&255.
__global__ __launch_bounds__(1024)
void k2a_tpart(const unsigned* __restrict__ u_pk, float* __restrict__ t_part2)
{
    __shared__ float2 red[4][256];
    const int tid  = threadIdx.x;
    const int js   = tid >> 8;
    const int slot = tid & 255;           // slot = k*8 + zp
    const int b    = blockIdx.x >> 3;
    const int sl   = blockIdx.x & 7;

    // j = sl*256 + jj*4 + js
    const unsigned* up = u_pk + (size_t)b * 524288
                       + (size_t)(sl * 256 + js) * 256 + slot;
    float a0 = 0.f, a1 = 0.f;
#pragma unroll 8
    for (int jj = 0; jj < 64; ++jj) {
        unsigned v = up[(size_t)jj * 1024];
        a0 += bf_lo(v); a1 += bf_hi(v);
    }
    red[js][slot] = make_float2(a0, a1);
    __syncthreads();
    if (tid < 256) {
        float2 r0 = red[0][tid], r1 = red[1][tid], r2 = red[2][tid], r3 = red[3][tid];
        float2 o;
        o.x = (r0.x + r1.x) + (r2.x + r3.x);
        o.y = (r0.y + r1.y) + (r2.y + r3.y);
        reinterpret_cast<float2*>(t_part2)[(size_t)blockIdx.x * 256 + tid] = o;
    }
}

// ---------------- K2a2: reduce 8 slices -> t --------------------------------
__global__ __launch_bounds__(256)
void k2a2_t(const float* __restrict__ t_part2, float* __restrict__ t)
{
    const int idx = blockIdx.x * 256 + threadIdx.x;
    const int b = idx >> 9, loc = idx & 511;
    const float* p = t_part2 + (size_t)b * 4096 + loc;
    float s = 0.f;
#pragma unroll
    for (int sl = 0; sl < 8; ++sl) s += p[sl * 512];
    t[idx] = s;
}

// ---------------- K2b: logits + softmax + bias + s-partials (fused) ---------
// grid 2048 (= 32 b * 64 j-chunks of 32), block 256: k = tid&31, jl = tid>>5.
// u rows kept in registers across all phases (no re-read).
__global__ __launch_bounds__(256)
void k2b_fused(const unsigned* __restrict__ u_pk, const float* __restrict__ t,
               const float* __restrict__ bias, float* __restrict__ s_part)
{
    __shared__ float lc_lds[32][33];        // logits, then c (aliased slots)
    __shared__ float s_lds[8][32][16];
    const int tid = threadIdx.x;
    const int k   = tid & 31;
    const int jl  = tid >> 5;
    const int b   = blockIdx.x >> 6;
    const int jc  = blockIdx.x & 63;

    float tr[16];
    const float4* tp = reinterpret_cast<const float4*>(t + ((size_t)b * KK + k) * 16);
#pragma unroll
    for (int q = 0; q < 4; ++q) {
        float4 v = tp[q];
        tr[4 * q + 0] = v.x; tr[4 * q + 1] = v.y; tr[4 * q + 2] = v.z; tr[4 * q + 3] = v.w;
    }

    // phase 1: logits for 4 j's; keep u in registers
    uint4 ua[4], ud[4];
#pragma unroll
    for (int jj = 0; jj < 4; ++jj) {
        const int jL = jj * 8 + jl;
        const int jg = jc * 32 + jL;
        const uint4* up = reinterpret_cast<const uint4*>(
            u_pk + ((size_t)b * NN + jg) * 256 + k * 8);
        ua[jj] = up[0]; ud[jj] = up[1];
        float a0 = 0.f, a1 = 0.f;
        a0 = fmaf(bf_lo(ua[jj].x), tr[0],  a0); a1 = fmaf(bf_hi(ua[jj].x), tr[1],  a1);
        a0 = fmaf(bf_lo(ua[jj].y), tr[2],  a0); a1 = fmaf(bf_hi(ua[jj].y), tr[3],  a1);
        a0 = fmaf(bf_lo(ua[jj].z), tr[4],  a0); a1 = fmaf(bf_hi(ua[jj].z), tr[5],  a1);
        a0 = fmaf(bf_lo(ua[jj].w), tr[6],  a0); a1 = fmaf(bf_hi(ua[jj].w), tr[7],  a1);
        a0 = fmaf(bf_lo(ud[jj].x), tr[8],  a0); a1 = fmaf(bf_hi(ud[jj].x), tr[9],  a1);
        a0 = fmaf(bf_lo(ud[jj].y), tr[10], a0); a1 = fmaf(bf_hi(ud[jj].y), tr[11], a1);
        a0 = fmaf(bf_lo(ud[jj].z), tr[12], a0); a1 = fmaf(bf_hi(ud[jj].z), tr[13], a1);
        a0 = fmaf(bf_lo(ud[jj].w), tr[14], a0); a1 = fmaf(bf_hi(ud[jj].w), tr[15], a1);
        lc_lds[jL][k] = a0 + a1;
    }
    __syncthreads();

    // phase 2: softmax over k (remap: j = tid>>3, kq = tid&7, 8-lane shuffles)
    {
        const int j = tid >> 3, kq = tid & 7;
        float lv[4];
#pragma unroll
        for (int m = 0; m < 4; ++m) lv[m] = lc_lds[j][kq * 4 + m];
        float pm = fmaxf(fmaxf(lv[0], lv[1]), fmaxf(lv[2], lv[3]));
        pm = fmaxf(pm, __shfl_xor(pm, 1));
        pm = fmaxf(pm, __shfl_xor(pm, 2));
        pm = fmaxf(pm, __shfl_xor(pm, 4));
        float ev[4], ps = 0.f;
#pragma unroll
        for (int m = 0; m < 4; ++m) { ev[m] = __expf((lv[m] - pm) * 0.25f); ps += ev[m]; }
        ps += __shfl_xor(ps, 1);
        ps += __shfl_xor(ps, 2);
        ps += __shfl_xor(ps, 4);
        const float inv = 1.f / ps;
        const int jg = jc * 32 + j;
#pragma unroll
        for (int m = 0; m < 4; ++m)
            lv[m] = ev[m] * inv + bias[(size_t)(kq * 4 + m) * NN + jg];
        __syncthreads();   // all reads of logits done before overwriting with c
#pragma unroll
        for (int m = 0; m < 4; ++m) lc_lds[j][kq * 4 + m] = lv[m];
    }
    __syncthreads();

    // phase 3: s partial accumulation from register-held u
    float sacc[16];
#pragma unroll
    for (int z = 0; z < 16; ++z) sacc[z] = 0.f;
#pragma unroll
    for (int jj = 0; jj < 4; ++jj) {
        const float cv = lc_lds[jj * 8 + jl][k];
        const uint4 a = ua[jj], d = ud[jj];
        sacc[0]  = fmaf(cv, bf_lo(a.x), sacc[0]);  sacc[1]  = fmaf(cv, bf_hi(a.x), sacc[1]);
        sacc[2]  = fmaf(cv, bf_lo(a.y), sacc[2]);  sacc[3]  = fmaf(cv, bf_hi(a.y), sacc[3]);
        sacc[4]  = fmaf(cv, bf_lo(a.z), sacc[4]);  sacc[5]  = fmaf(cv, bf_hi(a.z), sacc[5]);
        sacc[6]  = fmaf(cv, bf_lo(a.w), sacc[6]);  sacc[7]  = fmaf(cv, bf_hi(a.w), sacc[7]);
        sacc[8]  = fmaf(cv, bf_lo(d.x), sacc[8]);  sacc[9]  = fmaf(cv, bf_hi(d.x), sacc[9]);
        sacc[10] = fmaf(cv, bf_lo(d.y), sacc[10]); sacc[11] = fmaf(cv, bf_hi(d.y), sacc[11]);
        sacc[12] = fmaf(cv, bf_lo(d.z), sacc[12]); sacc[13] = fmaf(cv, bf_hi(d.z), sacc[13]);
        sacc[14] = fmaf(cv, bf_lo(d.w), sacc[14]); sacc[15] = fmaf(cv, bf_hi(d.w), sacc[15]);
    }

    // phase 4: reduce over jl, write block s-partial
#pragma unroll
    for (int q = 0; q < 4; ++q)
        *reinterpret_cast<float4*>(&s_lds[jl][k][q * 4]) =
            make_float4(sacc[q * 4], sacc[q * 4 + 1], sacc[q * 4 + 2], sacc[q * 4 + 3]);
    __syncthreads();
    {
        const int kk = tid >> 3, zp = tid & 7;
        float2 o; o.x = 0.f; o.y = 0.f;
#pragma unroll
        for (int l = 0; l < 8; ++l) {
            o.x += s_lds[l][kk][2 * zp];
            o.y += s_lds[l][kk][2 * zp + 1];
        }
        reinterpret_cast<float2*>(s_part)[((size_t)b * 64 + jc) * 256 + kk * 8 + zp] = o;
    }
}

// ---------------- K4: reduce jc slices + squash -----------------------------
__global__ __launch_bounds__(256)
void k4_squash(const float* __restrict__ s_part, float* __restrict__ out)
{
    const int idx = blockIdx.x * 256 + threadIdx.x;
    const int b = idx >> 9, loc = idx & 511;
    const float* p = s_part + (size_t)b * 32768 + loc;
    float s = 0.f;
#pragma unroll 8
    for (int jc = 0; jc < 64; ++jc) s += p[jc * 512];
    float ss = s * s;
    ss += __shfl_xor(ss, 1);
    ss += __shfl_xor(ss, 2);
    ss += __shfl_xor(ss, 4);
    ss += __shfl_xor(ss, 8);
    const float n = sqrtf(ss);
    out[idx] = (1.f - 1.f / (__expf(n) + 1e-20f)) * (s / (n + 1e-20f));
}

// sentinel if workspace too small
__global__ void k_sentinel(float* __restrict__ out)
{
    out[blockIdx.x * 256 + threadIdx.x] = 12345.0f;
}

extern "C" void kernel_launch(void* const* d_in, const int* in_sizes, int n_in,
                              void* d_out, int out_size, void* d_ws, size_t ws_size,
                              hipStream_t stream)
{
    const float* x    = (const float*)d_in[0];
    const float* w    = (const float*)d_in[1];
    const float* bias = (const float*)d_in[2];
    float* out        = (float*)d_out;

    char* ws = (char*)d_ws;
    if (ws_size < WS_NEED) {
        k_sentinel<<<dim3(64), dim3(256), 0, stream>>>(out);
        return;
    }
    unsigned* u_pk = (unsigned*)(ws + WS_U);
    float* t_part2 = (float*)(ws + WS_TP2);
    float* t       = (float*)(ws + WS_T);
    float* s_part  = (float*)(ws + WS_SPART);

    k1_u     <<<dim3(2048), dim3(256),  0, stream>>>(x, w, u_pk);
    k2a_tpart<<<dim3(256),  dim3(1024), 0, stream>>>(u_pk, t_part2);
    k2a2_t   <<<dim3(64),   dim3(256),  0, stream>>>(t_part2, t);
    k2b_fused<<<dim3(2048), dim3(256),  0, stream>>>(u_pk, t, bias, s_part);
    k4_squash<<<dim3(64),   dim3(256),  0, stream>>>(s_part, out);
}

// Round 3
// 65.300 us; speedup vs baseline: 1.7711x; 1.0878x over previous
//
#include <hip/hip_runtime.h>

#define NN 2048
#define KK 32

// workspace layout (bytes):
//  u_pk   : [32 b][2048 j][32 k][8 zp] u32 (bf16 z-pairs)  64 MiB @ 0
//  t_part2: [32 b][8 sl][512] f32                         512 KiB @ 67108864
//  t      : [32 b][32 k][16 z] f32                         64 KiB @ 67633152
//  s_part : [32 b][64 jc][512] f32                          4 MiB @ 67698688
#define WS_U     0
#define WS_TP2   67108864UL
#define WS_T     67633152UL
#define WS_SPART 67698688UL
#define WS_NEED  71892992UL

__device__ __forceinline__ float bf_lo(unsigned v) { return __uint_as_float(v << 16); }
__device__ __forceinline__ float bf_hi(unsigned v) { return __uint_as_float(v & 0xffff0000u); }
__device__ __forceinline__ unsigned pack_bf16(float a, float b) {
    unsigned ua = __float_as_uint(a), ub = __float_as_uint(b);
    return ((ua + 0x8000u) >> 16) | ((ub + 0x8000u) & 0xffff0000u);
}

// ---------------- K1: pure projection u = x @ w (bf16 packed) ---------------
// grid 1024 (2 j per block), block 256: jj = tid>>7, k = (tid>>2)&31, zq = tid&3.
// w slice: 16 x dwordx4 per thread (256B, independent, issued upfront).
// u store: dwordx2 per b (two packed bf16 pairs).
__global__ __launch_bounds__(256)
void k1_u(const float* __restrict__ x, const float* __restrict__ w,
          unsigned* __restrict__ u_pk)
{
    __shared__ float x_lds[2][32][16];
    const int tid = threadIdx.x;
    const int jj  = tid >> 7;
    const int k   = (tid >> 2) & 31;
    const int zq  = tid & 3;
    const int j0  = blockIdx.x * 2;
    const int j   = j0 + jj;

    // stage x rows for both j's: 256 threads x one float4
    {
        const int jjx = tid >> 7, b = (tid >> 2) & 31, q = tid & 3;
        const float4 v = *reinterpret_cast<const float4*>(
            x + ((size_t)b * NN + j0 + jjx) * 16 + q * 4);
        *reinterpret_cast<float4*>(&x_lds[jjx][b][q * 4]) = v;
    }

    // w[k][j][i][4zq .. 4zq+3], i = 0..15 (each element read exactly once)
    const float4* w4 = reinterpret_cast<const float4*>(
        w + (((size_t)k * NN + j) * 16) * 16) + zq;
    float4 wr[16];
#pragma unroll
    for (int i = 0; i < 16; ++i) wr[i] = w4[i * 4];

    __syncthreads();

    unsigned* __restrict__ ub = u_pk + ((size_t)j * KK + k) * 8 + zq * 2;
#pragma unroll 2
    for (int b = 0; b < 32; ++b) {
        float xs[16];
#pragma unroll
        for (int q = 0; q < 4; ++q) {
            float4 v = *reinterpret_cast<const float4*>(&x_lds[jj][b][q * 4]);
            xs[q * 4 + 0] = v.x; xs[q * 4 + 1] = v.y;
            xs[q * 4 + 2] = v.z; xs[q * 4 + 3] = v.w;
        }
        float4 acc = make_float4(0.f, 0.f, 0.f, 0.f);
#pragma unroll
        for (int i = 0; i < 16; ++i) {
            acc.x = fmaf(xs[i], wr[i].x, acc.x);
            acc.y = fmaf(xs[i], wr[i].y, acc.y);
            acc.z = fmaf(xs[i], wr[i].z, acc.z);
            acc.w = fmaf(xs[i], wr[i].w, acc.w);
        }
        uint2 o;
        o.x = pack_bf16(acc.x, acc.y);
        o.y = pack_bf16(acc.z, acc.w);
        *reinterpret_cast<uint2*>(ub + (size_t)b * (NN * KK * 8)) = o;
    }
}

// ---------------- K2a: t partials = sum over j-slices of u (uint4 loads) ----
// grid 256 (= 32 b * 8 slices), block 1024: js = tid>>6 (16), sl64 = tid&63.
__global__ __launch_bounds__(1024)
void k2a_tpart(const unsigned* __restrict__ u_pk, float* __restrict__ t_part2)
{
    __shared__ float red[16][64][8];
    const int tid  = threadIdx.x;
    const int js   = tid >> 6;
    const int sl64 = tid & 63;            // uint4 slot: covers zp quads
    const int b    = blockIdx.x >> 3;
    const int slj  = blockIdx.x & 7;

    const uint4* up = reinterpret_cast<const uint4*>(
        u_pk + (size_t)b * 524288 + (size_t)(slj * 256 + js) * 256) + sl64;
    float a[8];
#pragma unroll
    for (int e = 0; e < 8; ++e) a[e] = 0.f;
#pragma unroll
    for (int it = 0; it < 16; ++it) {
        uint4 v = up[(size_t)it * (16 * 64)];
        a[0] += bf_lo(v.x); a[1] += bf_hi(v.x);
        a[2] += bf_lo(v.y); a[3] += bf_hi(v.y);
        a[4] += bf_lo(v.z); a[5] += bf_hi(v.z);
        a[6] += bf_lo(v.w); a[7] += bf_hi(v.w);
    }
#pragma unroll
    for (int e = 0; e < 8; ++e) red[js][sl64][e] = a[e];
    __syncthreads();
    if (tid < 512) {
        const int s = tid >> 3, e = tid & 7;
        float acc = 0.f;
#pragma unroll
        for (int r = 0; r < 16; ++r) acc += red[r][s][e];
        t_part2[((size_t)b * 8 + slj) * 512 + s * 8 + e] = acc;
    }
}

// ---------------- K2a2: reduce 8 slices -> t (float4) -----------------------
__global__ __launch_bounds__(256)
void k2a2_t(const float* __restrict__ t_part2, float* __restrict__ t)
{
    const int idx4 = blockIdx.x * 256 + threadIdx.x;   // 4096 float4s
    const int b = idx4 >> 7, loc4 = idx4 & 127;
    const float4* p = reinterpret_cast<const float4*>(t_part2) + (size_t)b * 1024 + loc4;
    float4 s = make_float4(0.f, 0.f, 0.f, 0.f);
#pragma unroll
    for (int sl = 0; sl < 8; ++sl) {
        float4 v = p[sl * 128];
        s.x += v.x; s.y += v.y; s.z += v.z; s.w += v.w;
    }
    reinterpret_cast<float4*>(t)[idx4] = s;
}

// ---------------- K2b: logits + softmax + bias + s-partials (fused) ---------
// grid 2048 (= 32 b * 64 j-chunks of 32), block 256: k = tid&31, jl = tid>>5.
__global__ __launch_bounds__(256)
void k2b_fused(const unsigned* __restrict__ u_pk, const float* __restrict__ t,
               const float* __restrict__ bias, float* __restrict__ s_part)
{
    __shared__ float lc_lds[32][33];
    __shared__ float s_lds[8][32][16];
    const int tid = threadIdx.x;
    const int k   = tid & 31;
    const int jl  = tid >> 5;
    const int b   = blockIdx.x >> 6;
    const int jc  = blockIdx.x & 63;

    float tr[16];
    const float4* tp = reinterpret_cast<const float4*>(t + ((size_t)b * KK + k) * 16);
#pragma unroll
    for (int q = 0; q < 4; ++q) {
        float4 v = tp[q];
        tr[4 * q + 0] = v.x; tr[4 * q + 1] = v.y; tr[4 * q + 2] = v.z; tr[4 * q + 3] = v.w;
    }

    uint4 ua[4], ud[4];
#pragma unroll
    for (int jj = 0; jj < 4; ++jj) {
        const int jL = jj * 8 + jl;
        const int jg = jc * 32 + jL;
        const uint4* up = reinterpret_cast<const uint4*>(
            u_pk + ((size_t)b * NN + jg) * 256 + k * 8);
        ua[jj] = up[0]; ud[jj] = up[1];
        float a0 = 0.f, a1 = 0.f;
        a0 = fmaf(bf_lo(ua[jj].x), tr[0],  a0); a1 = fmaf(bf_hi(ua[jj].x), tr[1],  a1);
        a0 = fmaf(bf_lo(ua[jj].y), tr[2],  a0); a1 = fmaf(bf_hi(ua[jj].y), tr[3],  a1);
        a0 = fmaf(bf_lo(ua[jj].z), tr[4],  a0); a1 = fmaf(bf_hi(ua[jj].z), tr[5],  a1);
        a0 = fmaf(bf_lo(ua[jj].w), tr[6],  a0); a1 = fmaf(bf_hi(ua[jj].w), tr[7],  a1);
        a0 = fmaf(bf_lo(ud[jj].x), tr[8],  a0); a1 = fmaf(bf_hi(ud[jj].x), tr[9],  a1);
        a0 = fmaf(bf_lo(ud[jj].y), tr[10], a0); a1 = fmaf(bf_hi(ud[jj].y), tr[11], a1);
        a0 = fmaf(bf_lo(ud[jj].z), tr[12], a0); a1 = fmaf(bf_hi(ud[jj].z), tr[13], a1);
        a0 = fmaf(bf_lo(ud[jj].w), tr[14], a0); a1 = fmaf(bf_hi(ud[jj].w), tr[15], a1);
        lc_lds[jL][k] = a0 + a1;
    }
    __syncthreads();

    {
        const int jq = tid >> 3, kq = tid & 7;
        float lv[4];
#pragma unroll
        for (int m = 0; m < 4; ++m) lv[m] = lc_lds[jq][kq * 4 + m];
        float pm = fmaxf(fmaxf(lv[0], lv[1]), fmaxf(lv[2], lv[3]));
        pm = fmaxf(pm, __shfl_xor(pm, 1));
        pm = fmaxf(pm, __shfl_xor(pm, 2));
        pm = fmaxf(pm, __shfl_xor(pm, 4));
        float ev[4], ps = 0.f;
#pragma unroll
        for (int m = 0; m < 4; ++m) { ev[m] = __expf((lv[m] - pm) * 0.25f); ps += ev[m]; }
        ps += __shfl_xor(ps, 1);
        ps += __shfl_xor(ps, 2);
        ps += __shfl_xor(ps, 4);
        const float inv = 1.f / ps;
        const int jg = jc * 32 + jq;
#pragma unroll
        for (int m = 0; m < 4; ++m)
            lv[m] = ev[m] * inv + bias[(size_t)(kq * 4 + m) * NN + jg];
        __syncthreads();
#pragma unroll
        for (int m = 0; m < 4; ++m) lc_lds[jq][kq * 4 + m] = lv[m];
    }
    __syncthreads();

    float sacc[16];
#pragma unroll
    for (int z = 0; z < 16; ++z) sacc[z] = 0.f;
#pragma unroll
    for (int jj = 0; jj < 4; ++jj) {
        const float cv = lc_lds[jj * 8 + jl][k];
        const uint4 a = ua[jj], d = ud[jj];
        sacc[0]  = fmaf(cv, bf_lo(a.x), sacc[0]);  sacc[1]  = fmaf(cv, bf_hi(a.x), sacc[1]);
        sacc[2]  = fmaf(cv, bf_lo(a.y), sacc[2]);  sacc[3]  = fmaf(cv, bf_hi(a.y), sacc[3]);
        sacc[4]  = fmaf(cv, bf_lo(a.z), sacc[4]);  sacc[5]  = fmaf(cv, bf_hi(a.z), sacc[5]);
        sacc[6]  = fmaf(cv, bf_lo(a.w), sacc[6]);  sacc[7]  = fmaf(cv, bf_hi(a.w), sacc[7]);
        sacc[8]  = fmaf(cv, bf_lo(d.x), sacc[8]);  sacc[9]  = fmaf(cv, bf_hi(d.x), sacc[9]);
        sacc[10] = fmaf(cv, bf_lo(d.y), sacc[10]); sacc[11] = fmaf(cv, bf_hi(d.y), sacc[11]);
        sacc[12] = fmaf(cv, bf_lo(d.z), sacc[12]); sacc[13] = fmaf(cv, bf_hi(d.z), sacc[13]);
        sacc[14] = fmaf(cv, bf_lo(d.w), sacc[14]); sacc[15] = fmaf(cv, bf_hi(d.w), sacc[15]);
    }

#pragma unroll
    for (int q = 0; q < 4; ++q)
        *reinterpret_cast<float4*>(&s_lds[jl][k][q * 4]) =
            make_float4(sacc[q * 4], sacc[q * 4 + 1], sacc[q * 4 + 2], sacc[q * 4 + 3]);
    __syncthreads();
    {
        const int kk = tid >> 3, zp = tid & 7;
        float2 o; o.x = 0.f; o.y = 0.f;
#pragma unroll
        for (int l = 0; l < 8; ++l) {
            o.x += s_lds[l][kk][2 * zp];
            o.y += s_lds[l][kk][2 * zp + 1];
        }
        reinterpret_cast<float2*>(s_part)[((size_t)b * 64 + jc) * 256 + kk * 8 + zp] = o;
    }
}

// ---------------- K4: reduce jc slices + squash (float4) --------------------
// grid 16, block 256: one float4 (= 4 z of one (b,k)) per thread.
__global__ __launch_bounds__(256)
void k4_squash(const float* __restrict__ s_part, float* __restrict__ out)
{
    const int idx4 = blockIdx.x * 256 + threadIdx.x;   // 4096 float4s
    const int b = idx4 >> 7, loc4 = idx4 & 127;        // loc4 = k*4 + zq
    const float4* p = reinterpret_cast<const float4*>(s_part) + (size_t)b * 8192 + loc4;
    float4 s = make_float4(0.f, 0.f, 0.f, 0.f);
#pragma unroll 8
    for (int jc = 0; jc < 64; ++jc) {
        float4 v = p[jc * 128];
        s.x += v.x; s.y += v.y; s.z += v.z; s.w += v.w;
    }
    float ss = s.x * s.x + s.y * s.y + s.z * s.z + s.w * s.w;
    ss += __shfl_xor(ss, 1);   // lanes zq 0..3 of same (b,k)
    ss += __shfl_xor(ss, 2);
    const float n = sqrtf(ss);
    const float sc = (1.f - 1.f / (__expf(n) + 1e-20f)) / (n + 1e-20f);
    float4 o; o.x = s.x * sc; o.y = s.y * sc; o.z = s.z * sc; o.w = s.w * sc;
    reinterpret_cast<float4*>(out)[idx4] = o;
}

// sentinel if workspace too small
__global__ void k_sentinel(float* __restrict__ out)
{
    out[blockIdx.x * 256 + threadIdx.x] = 12345.0f;
}

extern "C" void kernel_launch(void* const* d_in, const int* in_sizes, int n_in,
                              void* d_out, int out_size, void* d_ws, size_t ws_size,
                              hipStream_t stream)
{
    const float* x    = (const float*)d_in[0];
    const float* w    = (const float*)d_in[1];
    const float* bias = (const float*)d_in[2];
    float* out        = (float*)d_out;

    char* ws = (char*)d_ws;
    if (ws_size < WS_NEED) {
        k_sentinel<<<dim3(64), dim3(256), 0, stream>>>(out);
        return;
    }
    unsigned* u_pk = (unsigned*)(ws + WS_U);
    float* t_part2 = (float*)(ws + WS_TP2);
    float* t       = (float*)(ws + WS_T);
    float* s_part  = (float*)(ws + WS_SPART);

    k1_u     <<<dim3(1024), dim3(256),  0, stream>>>(x, w, u_pk);
    k2a_tpart<<<dim3(256),  dim3(1024), 0, stream>>>(u_pk, t_part2);
    k2a2_t   <<<dim3(16),   dim3(256),  0, stream>>>(t_part2, t);
    k2b_fused<<<dim3(2048), dim3(256),  0, stream>>>(u_pk, t, bias, s_part);
    k4_squash<<<dim3(16),   dim3(256),  0, stream>>>(s_part, out);
}